// Round 1
// baseline (242.484 us; speedup 1.0000x reference)
//
#include <hip/hip_runtime.h>

// out = x + alpha * (x @ W^T),  W scattered dense from COO (dups sum).
// M=8192 (4*2048), K=N=2048. Strategy: scatter->dense W fp32, convert W,x to
// bf16, then m97-structure bf16 MFMA GEMM (128x128 tile, BK=32, gemm_bt:
// both operands [rows][K]), fused epilogue out = x + alpha*acc.
//
// Workspace layout (needs 40 MB):
//   [0,16MB)   W_f32 (scatter target), later overwritten by...
//   [0,32MB)   x_bf16 (written AFTER W_f32 has been consumed; stream-ordered)
//   [32,40MB)  W_bf16

typedef unsigned short u16;
typedef __attribute__((ext_vector_type(8))) short bf16x8;
typedef __attribute__((ext_vector_type(4))) float f32x4;

#define HID 2048
#define BM 128
#define BN 128
#define BK 32

__device__ __forceinline__ u16 f2bf(float f) {
    unsigned u = __builtin_bit_cast(unsigned, f);
    u += 0x7fffu + ((u >> 16) & 1u);   // RNE (inputs are finite normals)
    return (u16)(u >> 16);
}

__global__ void cvt_f32_bf16_kernel(const float* __restrict__ in,
                                    u16* __restrict__ out, int n8) {
    int stride = gridDim.x * blockDim.x;
    for (int i = blockIdx.x * blockDim.x + threadIdx.x; i < n8; i += stride) {
        const float4* p = (const float4*)in + (size_t)i * 2;
        float4 a = p[0], b = p[1];
        uint4 o;
        o.x = (unsigned)f2bf(a.x) | ((unsigned)f2bf(a.y) << 16);
        o.y = (unsigned)f2bf(a.z) | ((unsigned)f2bf(a.w) << 16);
        o.z = (unsigned)f2bf(b.x) | ((unsigned)f2bf(b.y) << 16);
        o.w = (unsigned)f2bf(b.z) | ((unsigned)f2bf(b.w) << 16);
        ((uint4*)out)[i] = o;
    }
}

__global__ void scatter_coo_kernel(const int* __restrict__ idx,
                                   const float* __restrict__ vals,
                                   float* __restrict__ W, int nnz) {
    int n = blockIdx.x * blockDim.x + threadIdx.x;
    if (n < nnz) {
        int i = idx[n];         // row of W (output feature)
        int j = idx[nnz + n];   // col of W (input feature)
        atomicAdd(W + (size_t)i * HID + j, vals[n]);
    }
}

#define GLDS(gsrc, ldst)                                                   \
    __builtin_amdgcn_global_load_lds(                                      \
        (const __attribute__((address_space(1))) void*)(gsrc),             \
        (__attribute__((address_space(3))) void*)(ldst), 16, 0, 0)

// C[m,n] = sum_k A[m,k]*B[n,k]; out = Xf + alpha*C. A=[M][K] bf16, B=[N][K] bf16.
__global__ __launch_bounds__(256) void gemm_bt_kernel(
        const u16* __restrict__ A, const u16* __restrict__ B,
        const float* __restrict__ Xf, const float* __restrict__ alphap,
        float* __restrict__ out, int M) {
    __shared__ u16 As[BM * BK];
    __shared__ u16 Bs[BN * BK];

    const int t = threadIdx.x;
    const int lane = t & 63;
    const int w = t >> 6;            // wave 0..3
    const int wr = w >> 1, wc = w & 1;
    const int fr = lane & 15;        // fragment row/col
    const int kg = lane >> 4;        // k-group 0..3

    // XCD-aware bijective swizzle (nwg = 1024, divisible by 8)
    const int nwg = gridDim.x;
    const int cpx = nwg >> 3;
    const int bid = blockIdx.x;
    const int swz = (bid & 7) * cpx + (bid >> 3);
    const int nbn = HID / BN;        // 16
    const int bm = swz / nbn;
    const int bn = swz % nbn;
    const size_t rowBase = (size_t)bm * BM;
    const size_t colBase = (size_t)bn * BN;

    const int lrow = lane >> 2;          // 0..15
    const int lcol = (lane & 3) * 8;     // element offset (16B granules)

    f32x4 acc[4][4] = {};

    const int KT = HID / BK;             // 64
    for (int kt = 0; kt < KT; ++kt) {
        const int k0 = kt * BK;
#pragma unroll
        for (int p = 0; p < 2; ++p) {
            const int chunk = (p << 2) + w;          // 0..7, 1KB each
            const int row = (chunk << 4) + lrow;     // tile row 0..127
            GLDS(A + (rowBase + row) * HID + k0 + lcol, &As[chunk * 512 + lane * 8]);
            GLDS(B + (colBase + row) * HID + k0 + lcol, &Bs[chunk * 512 + lane * 8]);
        }
        __syncthreads();

        bf16x8 af[4], bfv[4];
#pragma unroll
        for (int mi = 0; mi < 4; ++mi)
            af[mi] = *(const bf16x8*)&As[(wr * 64 + mi * 16 + fr) * BK + kg * 8];
#pragma unroll
        for (int ni = 0; ni < 4; ++ni)
            bfv[ni] = *(const bf16x8*)&Bs[(wc * 64 + ni * 16 + fr) * BK + kg * 8];
#pragma unroll
        for (int mi = 0; mi < 4; ++mi)
#pragma unroll
            for (int ni = 0; ni < 4; ++ni)
                acc[mi][ni] = __builtin_amdgcn_mfma_f32_16x16x32_bf16(
                    af[mi], bfv[ni], acc[mi][ni], 0, 0, 0);
        __syncthreads();
    }

    const float alphav = *alphap;
#pragma unroll
    for (int mi = 0; mi < 4; ++mi) {
#pragma unroll
        for (int ni = 0; ni < 4; ++ni) {
            f32x4 c = acc[mi][ni];
            const size_t gn = colBase + wc * 64 + ni * 16 + fr;
#pragma unroll
            for (int r = 0; r < 4; ++r) {
                const size_t gm = rowBase + wr * 64 + mi * 16 + kg * 4 + r;
                const size_t o = gm * HID + gn;
                out[o] = Xf[o] + alphav * c[r];
            }
        }
    }
}

extern "C" void kernel_launch(void* const* d_in, const int* in_sizes, int n_in,
                              void* d_out, int out_size, void* d_ws, size_t ws_size,
                              hipStream_t stream) {
    const float* x     = (const float*)d_in[0];
    const int*   idx   = (const int*)d_in[1];
    const float* vals  = (const float*)d_in[2];
    const float* alpha = (const float*)d_in[3];
    float* out = (float*)d_out;

    const int nnz = in_sizes[2];
    const int M = in_sizes[0] / HID;      // 8192

    float* Wf = (float*)d_ws;                                   // 16 MB
    u16*   Xb = (u16*)d_ws;                                     // 32 MB (reuses Wf region)
    u16*   Wb = (u16*)((char*)d_ws + (size_t)32 * 1024 * 1024); // 8 MB

    // 1) zero W, scatter-add COO (duplicates sum via atomics)
    hipMemsetAsync(Wf, 0, (size_t)HID * HID * sizeof(float), stream);
    scatter_coo_kernel<<<(nnz + 255) / 256, 256, 0, stream>>>(idx, vals, Wf, nnz);

    // 2) W fp32 -> bf16
    cvt_f32_bf16_kernel<<<2048, 256, 0, stream>>>(Wf, Wb, (HID * HID) / 8);

    // 3) x fp32 -> bf16 (overwrites Wf region; stream-ordered after step 2)
    cvt_f32_bf16_kernel<<<2048, 256, 0, stream>>>(x, Xb, (M * HID) / 8);

    // 4) GEMM + fused epilogue
    const int grid = (M / BM) * (HID / BN);   // 1024
    gemm_bt_kernel<<<grid, 256, 0, stream>>>(Xb, Wb, x, alpha, out, M);
}

// Round 2
// 212.020 us; speedup vs baseline: 1.1437x; 1.1437x over previous
//
#include <hip/hip_runtime.h>

// out = x + alpha * (x @ W^T).  M=8192, N=K=2048.
// R2: 256x256 deep-pipelined bf16 MFMA GEMM, BK=32, 8 waves, ring-4 LDS slots
// (128KB), stage lead 3 tiles, counted vmcnt(8), raw s_barrier, setprio,
// XOR-granule LDS swizzle (2-way reads). Aux: scatter->dense W, fused convert.

typedef unsigned short u16;
typedef __attribute__((ext_vector_type(8))) short bf16x8;
typedef __attribute__((ext_vector_type(4))) float f32x4;

#define HID 2048
#define BM 256
#define BN 256
#define BK 32
#define NT (HID / BK)                 // 64 K-tiles
#define SLOT_ELEMS (BM * BK + BN * BK) // 16384 u16 = 32KB per slot
#define HALF_ELEMS (128 * BK)          // 4096 u16 per half-tile

__device__ __forceinline__ u16 f2bf(float f) {
    unsigned u = __builtin_bit_cast(unsigned, f);
    u += 0x7fffu + ((u >> 16) & 1u);   // RNE (finite normals)
    return (u16)(u >> 16);
}

__device__ __forceinline__ void cvt8(const float* __restrict__ src,
                                     u16* __restrict__ dst, int i) {
    const float4* p = (const float4*)src + (size_t)i * 2;
    float4 a = p[0], b = p[1];
    uint4 o;
    o.x = (unsigned)f2bf(a.x) | ((unsigned)f2bf(a.y) << 16);
    o.y = (unsigned)f2bf(a.z) | ((unsigned)f2bf(a.w) << 16);
    o.z = (unsigned)f2bf(b.x) | ((unsigned)f2bf(b.y) << 16);
    o.w = (unsigned)f2bf(b.z) | ((unsigned)f2bf(b.w) << 16);
    ((uint4*)dst)[i] = o;
}

__global__ void cvt_f32_bf16_kernel(const float* __restrict__ in,
                                    u16* __restrict__ out, int n8) {
    int stride = gridDim.x * blockDim.x;
    for (int i = blockIdx.x * blockDim.x + threadIdx.x; i < n8; i += stride)
        cvt8(in, out, i);
}

__global__ void cvt_both_kernel(const float* __restrict__ w,
                                const float* __restrict__ x,
                                u16* __restrict__ wb, u16* __restrict__ xb,
                                int n8w, int n8x) {
    int stride = gridDim.x * blockDim.x;
    int total = n8w + n8x;
    for (int i = blockIdx.x * blockDim.x + threadIdx.x; i < total; i += stride) {
        if (i < n8w) cvt8(w, wb, i);
        else         cvt8(x, xb, i - n8w);
    }
}

__global__ void scatter_coo_kernel(const int* __restrict__ idx,
                                   const float* __restrict__ vals,
                                   float* __restrict__ W, int nnz) {
    int n = blockIdx.x * blockDim.x + threadIdx.x;
    if (n < nnz) {
        int i = idx[n];         // row of W
        int j = idx[nnz + n];   // col of W
        atomicAdd(W + (size_t)i * HID + j, vals[n]);
    }
}

#define GLDS(gsrc, ldst)                                                   \
    __builtin_amdgcn_global_load_lds(                                      \
        (const __attribute__((address_space(1))) void*)(gsrc),             \
        (__attribute__((address_space(3))) void*)(ldst), 16, 0, 0)

// C[m,n] = sum_k A[m,k]*B[n,k]; out = Xf + alpha*C.
__global__ __launch_bounds__(512, 2) void gemm8_kernel(
        const u16* __restrict__ A,   // [8192][2048] bf16
        const u16* __restrict__ B,   // [2048][2048] bf16
        const float* __restrict__ Xf,
        const float* __restrict__ alphap,
        float* __restrict__ out) {
    __shared__ u16 lds[4 * SLOT_ELEMS];   // 128 KB: 4 slots x (A 16KB + B 16KB)

    const int t = threadIdx.x;
    const int lane = t & 63;
    const int w = t >> 6;              // wave 0..7
    const int wr = w >> 2;             // 0..1  (row quadrant of waves)
    const int wc = w & 3;              // 0..3  (col quadrant)
    const int fr = lane & 15;
    const int kg = lane >> 4;

    // XCD-aware bijective swizzle (256 blocks, 8 XCDs, 32 each)
    const int bid = blockIdx.x;
    const int swz = (bid & 7) * 32 + (bid >> 3);
    const int bm = swz >> 3;           // 0..31
    const int bn = swz & 7;            // 0..7
    const size_t rowBase = (size_t)bm * BM;
    const size_t colBase = (size_t)bn * BN;

    // ---- staging constants (per thread) ----
    // Each wave stages 16 rows x 64B per instruction (1KB). Linear LDS dest,
    // inverse-swizzled global source (rule #21): granule g^=(row>>1)&3.
    const int srow = (w << 4) + (lane >> 2);            // 0..127 within half
    const int sg = (lane & 3) ^ ((srow >> 1) & 3);      // pre-swizzled source granule
    const u16* aSrc = A + (rowBase + srow) * HID + sg * 8;
    const u16* bSrc = B + (colBase + srow) * HID + sg * 8;
    const int ldst = (w << 9) + (lane << 3);            // linear dest within half

    // ---- fragment-read constant: swizzled granule. (row>>1)&3 == (fr>>1)&3
    const int gread = kg ^ ((fr >> 1) & 3);

    f32x4 acc[8][4] = {};

    // ---- prologue: stage tiles 0,1,2 (lead-3) ----
    for (int pt = 0; pt < 3; ++pt) {
        u16* slot = lds + (pt & 3) * SLOT_ELEMS;
        const u16* as = aSrc + pt * BK;
        const u16* bs = bSrc + pt * BK;
        GLDS(as,             slot + ldst);
        GLDS(bs,             slot + 2 * HALF_ELEMS + ldst);
        GLDS(as + 128 * HID, slot + HALF_ELEMS + ldst);
        GLDS(bs + 128 * HID, slot + 3 * HALF_ELEMS + ldst);
    }
    asm volatile("s_waitcnt vmcnt(8)" ::: "memory");   // tile 0 landed
    __builtin_amdgcn_s_barrier();
    __builtin_amdgcn_sched_barrier(0);

    // ---- main loop: compute tile tt from slot tt%4, stage tile tt+3 ----
#pragma unroll 1
    for (int tt = 0; tt < NT; ++tt) {
        u16* slot  = lds + (tt & 3) * SLOT_ELEMS;
        u16* slot3 = lds + ((tt + 3) & 3) * SLOT_ELEMS;
        const int t3 = tt + 3;
        const u16* as3 = aSrc + t3 * BK;
        const u16* bs3 = bSrc + t3 * BK;
        const u16* aRd = slot + (wr * 128 + fr) * BK + gread * 8;
        const u16* bRd = slot + 2 * HALF_ELEMS + (wc * 64 + fr) * BK + gread * 8;

        bf16x8 b[4];

        // ======== phase 0: rows m0..3 ========
        bf16x8 a0[4];
#pragma unroll
        for (int m = 0; m < 4; ++m)
            a0[m] = *(const bf16x8*)(aRd + m * 16 * BK);
#pragma unroll
        for (int n = 0; n < 4; ++n)
            b[n] = *(const bf16x8*)(bRd + n * 16 * BK);
        if (t3 < NT) {
            GLDS(as3, slot3 + ldst);
            GLDS(bs3, slot3 + 2 * HALF_ELEMS + ldst);
        }
        asm volatile("s_waitcnt lgkmcnt(0)" ::: "memory"); // reads done pre-barrier
        __builtin_amdgcn_s_barrier();
        __builtin_amdgcn_sched_barrier(0);
        __builtin_amdgcn_s_setprio(1);
#pragma unroll
        for (int m = 0; m < 4; ++m)
#pragma unroll
            for (int n = 0; n < 4; ++n)
                acc[m][n] = __builtin_amdgcn_mfma_f32_16x16x32_bf16(
                    a0[m], b[n], acc[m][n], 0, 0, 0);
        __builtin_amdgcn_s_setprio(0);

        // ======== phase 1: rows m4..7 ========
        bf16x8 a1[4];
#pragma unroll
        for (int m = 0; m < 4; ++m)
            a1[m] = *(const bf16x8*)(aRd + (m + 4) * 16 * BK);
        if (t3 < NT) {
            GLDS(as3 + 128 * HID, slot3 + HALF_ELEMS + ldst);
            GLDS(bs3 + 128 * HID, slot3 + 3 * HALF_ELEMS + ldst);
        }
        asm volatile("s_waitcnt lgkmcnt(0)" ::: "memory");
        // counted vmcnt once per K-tile: allow tiles tt+2,tt+3 in flight,
        // guarantee tile tt+1 landed before its reads. Drain 8->4->0 at tail.
        if (tt < NT - 3)       asm volatile("s_waitcnt vmcnt(8)" ::: "memory");
        else if (tt == NT - 3) asm volatile("s_waitcnt vmcnt(4)" ::: "memory");
        else if (tt == NT - 2) asm volatile("s_waitcnt vmcnt(0)" ::: "memory");
        __builtin_amdgcn_s_barrier();
        __builtin_amdgcn_sched_barrier(0);
        __builtin_amdgcn_s_setprio(1);
#pragma unroll
        for (int m = 0; m < 4; ++m)
#pragma unroll
            for (int n = 0; n < 4; ++n)
                acc[m + 4][n] = __builtin_amdgcn_mfma_f32_16x16x32_bf16(
                    a1[m], b[n], acc[m + 4][n], 0, 0, 0);
        __builtin_amdgcn_s_setprio(0);
    }

    // ---- epilogue: out = Xf + alpha*acc ----
    const float alphav = *alphap;
#pragma unroll
    for (int m = 0; m < 8; ++m) {
#pragma unroll
        for (int n = 0; n < 4; ++n) {
            f32x4 c = acc[m][n];
            const size_t gn = colBase + wc * 64 + n * 16 + fr;
#pragma unroll
            for (int j = 0; j < 4; ++j) {
                const size_t gm = rowBase + wr * 128 + m * 16 + kg * 4 + j;
                const size_t o = gm * HID + gn;
                out[o] = Xf[o] + alphav * c[j];
            }
        }
    }
}

extern "C" void kernel_launch(void* const* d_in, const int* in_sizes, int n_in,
                              void* d_out, int out_size, void* d_ws, size_t ws_size,
                              hipStream_t stream) {
    const float* x     = (const float*)d_in[0];
    const int*   idx   = (const int*)d_in[1];
    const float* vals  = (const float*)d_in[2];
    const float* alpha = (const float*)d_in[3];
    float* out = (float*)d_out;

    const int nnz = in_sizes[2];
    const size_t MB = 1024 * 1024;
    const int n8W = (HID * HID) / 8;        // 524288
    const int n8X = in_sizes[0] / 8;        // 2097152

    if (ws_size >= 56 * MB) {
        // disjoint layout: Xb [0,32M), Wb [32M,40M), Wf [40M,56M)
        u16*   Xb = (u16*)d_ws;
        u16*   Wb = (u16*)((char*)d_ws + 32 * MB);
        float* Wf = (float*)((char*)d_ws + 40 * MB);
        hipMemsetAsync(Wf, 0, (size_t)HID * HID * sizeof(float), stream);
        scatter_coo_kernel<<<(nnz + 255) / 256, 256, 0, stream>>>(idx, vals, Wf, nnz);
        cvt_both_kernel<<<2048, 256, 0, stream>>>(Wf, x, Wb, Xb, n8W, n8X);
        gemm8_kernel<<<256, 512, 0, stream>>>(Xb, Wb, x, alpha, out);
    } else {
        // fallback: overlapping layout (W consumed before Xb written)
        float* Wf = (float*)d_ws;
        u16*   Xb = (u16*)d_ws;
        u16*   Wb = (u16*)((char*)d_ws + 32 * MB);
        hipMemsetAsync(Wf, 0, (size_t)HID * HID * sizeof(float), stream);
        scatter_coo_kernel<<<(nnz + 255) / 256, 256, 0, stream>>>(idx, vals, Wf, nnz);
        cvt_f32_bf16_kernel<<<2048, 256, 0, stream>>>(Wf, Wb, n8W);
        cvt_f32_bf16_kernel<<<2048, 256, 0, stream>>>(x, Xb, n8X);
        gemm8_kernel<<<256, 512, 0, stream>>>(Xb, Wb, x, alpha, out);
    }
}

// Round 3
// 211.399 us; speedup vs baseline: 1.1470x; 1.0029x over previous
//
#include <hip/hip_runtime.h>

// out = x + alpha * (x @ W^T).  M=8192, N=K=2048.
// R3: GEMM BM=128 BN=256 BK=32, 8 waves, ring-3 LDS (72KB) lead-2,
// ONE barrier per K-tile, counted vmcnt(3), 512 blocks (2/CU) so epilogue
// overlaps co-resident block. Epilogue reads bf16 Xb, nontemporal stores.
// Aux: memset -> fused(scatter + cvtX) -> cvtW -> gemm.

typedef unsigned short u16;
typedef __attribute__((ext_vector_type(8))) short bf16x8;
typedef __attribute__((ext_vector_type(4))) float f32x4;

#define HID 2048
#define BM 128
#define BN 256
#define BK 32
#define NT (HID / BK)              // 64
#define ASZ (BM * BK)              // 4096 u16 (8KB)
#define BSZ (BN * BK)              // 8192 u16 (16KB)
#define SLOT (ASZ + BSZ)           // 12288 u16 (24KB)

__device__ __forceinline__ u16 f2bf(float f) {
    unsigned u = __builtin_bit_cast(unsigned, f);
    u += 0x7fffu + ((u >> 16) & 1u);   // RNE (finite normals)
    return (u16)(u >> 16);
}

__device__ __forceinline__ void cvt8(const float* __restrict__ src,
                                     u16* __restrict__ dst, int i) {
    const float4* p = (const float4*)src + (size_t)i * 2;
    float4 a = p[0], b = p[1];
    uint4 o;
    o.x = (unsigned)f2bf(a.x) | ((unsigned)f2bf(a.y) << 16);
    o.y = (unsigned)f2bf(a.z) | ((unsigned)f2bf(a.w) << 16);
    o.z = (unsigned)f2bf(b.x) | ((unsigned)f2bf(b.y) << 16);
    o.w = (unsigned)f2bf(b.z) | ((unsigned)f2bf(b.w) << 16);
    ((uint4*)dst)[i] = o;
}

__global__ void cvt_f32_bf16_kernel(const float* __restrict__ in,
                                    u16* __restrict__ out, int n8) {
    int stride = gridDim.x * blockDim.x;
    for (int i = blockIdx.x * blockDim.x + threadIdx.x; i < n8; i += stride)
        cvt8(in, out, i);
}

__global__ void scatter_coo_kernel(const int* __restrict__ idx,
                                   const float* __restrict__ vals,
                                   float* __restrict__ W, int nnz) {
    int n = blockIdx.x * blockDim.x + threadIdx.x;
    if (n < nnz)
        atomicAdd(W + (size_t)idx[n] * HID + idx[nnz + n], vals[n]);
}

// fused: COO scatter (gid < nnz) + x -> bf16 grid-stride convert
__global__ void prep_kernel(const int* __restrict__ idx,
                            const float* __restrict__ vals,
                            float* __restrict__ W, int nnz,
                            const float* __restrict__ x,
                            u16* __restrict__ xb, int n8x) {
    int gid = blockIdx.x * blockDim.x + threadIdx.x;
    if (gid < nnz)
        atomicAdd(W + (size_t)idx[gid] * HID + idx[nnz + gid], vals[gid]);
    int stride = gridDim.x * blockDim.x;
    for (int i = gid; i < n8x; i += stride)
        cvt8(x, xb, i);
}

#define GLDS(gsrc, ldst)                                                   \
    __builtin_amdgcn_global_load_lds(                                      \
        (const __attribute__((address_space(1))) void*)(gsrc),             \
        (__attribute__((address_space(3))) void*)(ldst), 16, 0, 0)

// C[m,n] = sum_k A[m,k]*B[n,k]; out = bf2f(Xb) + alpha*C.
__global__ __launch_bounds__(512, 4) void gemm3_kernel(
        const u16* __restrict__ A,   // [8192][2048] bf16
        const u16* __restrict__ B,   // [2048][2048] bf16
        const float* __restrict__ alphap,
        float* __restrict__ out) {
    __shared__ u16 lds[3 * SLOT];    // 72 KB

    const int t = threadIdx.x;
    const int lane = t & 63;
    const int w = t >> 6;            // 0..7
    const int wr = w >> 2;           // 0..1
    const int wc = w & 3;            // 0..3
    const int fr = lane & 15;
    const int kg = lane >> 4;

    // XCD-aware bijective swizzle: 512 blocks, 64 per XCD
    const int bid = blockIdx.x;
    const int swz = (bid & 7) * 64 + (bid >> 3);
    const int bm = swz >> 3;         // 0..63
    const int bn = swz & 7;          // 0..7
    const size_t rowBase = (size_t)bm * BM;
    const size_t colBase = (size_t)bn * BN;

    // ---- staging addresses (linear LDS dest, inverse-swizzled global src) ----
    const int srowA = (w << 4) + (lane >> 2);              // 0..127
    const int sgA = (lane & 3) ^ ((srowA >> 1) & 3);
    const u16* aSrc = A + (rowBase + srowA) * HID + sgA * 8;
    const int adst = w * 512 + lane * 8;

    const int srowB = (w << 5) + (lane >> 2);              // 0..255 (first 16)
    const int sgB = (lane & 3) ^ ((srowB >> 1) & 3);       // same for row+16
    const u16* bSrc0 = B + (colBase + srowB) * HID + sgB * 8;
    const u16* bSrc1 = bSrc0 + (size_t)16 * HID;
    const int bdst0 = ASZ + w * 1024 + lane * 8;
    const int bdst1 = bdst0 + 512;

    // fragment-read swizzled granule
    const int gread = kg ^ ((fr >> 1) & 3);
    const int aRdOff = (wr * 64 + fr) * BK + gread * 8;
    const int bRdOff = ASZ + (wc * 64 + fr) * BK + gread * 8;

    f32x4 acc[4][4] = {};

    // ---- prologue: stage tiles 0 (slot 0) and 1 (slot 1) ----
#pragma unroll
    for (int pt = 0; pt < 2; ++pt) {
        u16* s = lds + pt * SLOT;
        GLDS(aSrc + pt * BK, s + adst);
        GLDS(bSrc0 + pt * BK, s + bdst0);
        GLDS(bSrc1 + pt * BK, s + bdst1);
    }
    asm volatile("s_waitcnt vmcnt(3)" ::: "memory");   // tile 0 landed
    __builtin_amdgcn_s_barrier();
    __builtin_amdgcn_sched_barrier(0);

    int cur = 0;                      // tt % 3
#pragma unroll 1
    for (int tt = 0; tt < NT; ++tt) {
        u16* slot = lds + cur * SLOT;
        const int wIdx = cur + 2 >= 3 ? cur - 1 : cur + 2;   // (tt+2)%3
        u16* slotW = lds + wIdx * SLOT;

        // ds_read 8 fragments of tile tt
        bf16x8 a[4], b[4];
#pragma unroll
        for (int m = 0; m < 4; ++m)
            a[m] = *(const bf16x8*)(slot + aRdOff + m * 512);
#pragma unroll
        for (int n = 0; n < 4; ++n)
            b[n] = *(const bf16x8*)(slot + bRdOff + n * 512);

        // stage tile tt+2
        if (tt + 2 < NT) {
            const int koff = (tt + 2) * BK;
            GLDS(aSrc + koff, slotW + adst);
            GLDS(bSrc0 + koff, slotW + bdst0);
            GLDS(bSrc1 + koff, slotW + bdst1);
        }

        asm volatile("s_waitcnt lgkmcnt(0)" ::: "memory");
        __builtin_amdgcn_sched_barrier(0);
        if (tt <= NT - 3)      asm volatile("s_waitcnt vmcnt(3)" ::: "memory");
        else if (tt == NT - 2) asm volatile("s_waitcnt vmcnt(0)" ::: "memory");
        __builtin_amdgcn_s_barrier();
        __builtin_amdgcn_sched_barrier(0);

        __builtin_amdgcn_s_setprio(1);
#pragma unroll
        for (int m = 0; m < 4; ++m)
#pragma unroll
            for (int n = 0; n < 4; ++n)
                acc[m][n] = __builtin_amdgcn_mfma_f32_16x16x32_bf16(
                    a[m], b[n], acc[m][n], 0, 0, 0);
        __builtin_amdgcn_s_setprio(0);

        cur = cur == 2 ? 0 : cur + 1;
    }

    // ---- epilogue: out = bf16(x) + alpha*acc, nontemporal ----
    const float alphav = *alphap;
#pragma unroll
    for (int m = 0; m < 4; ++m) {
#pragma unroll
        for (int n = 0; n < 4; ++n) {
            f32x4 c = acc[m][n];
            const size_t gn = colBase + wc * 64 + n * 16 + fr;
#pragma unroll
            for (int j = 0; j < 4; ++j) {
                const size_t gm = rowBase + wr * 64 + m * 16 + kg * 4 + j;
                const size_t o = gm * HID + gn;
                unsigned xu = ((unsigned)A[o]) << 16;
                float xf = __builtin_bit_cast(float, xu);
                __builtin_nontemporal_store(xf + alphav * c[j], &out[o]);
            }
        }
    }
}

extern "C" void kernel_launch(void* const* d_in, const int* in_sizes, int n_in,
                              void* d_out, int out_size, void* d_ws, size_t ws_size,
                              hipStream_t stream) {
    const float* x     = (const float*)d_in[0];
    const int*   idx   = (const int*)d_in[1];
    const float* vals  = (const float*)d_in[2];
    const float* alpha = (const float*)d_in[3];
    float* out = (float*)d_out;

    const int nnz = in_sizes[2];
    const size_t MB = 1024 * 1024;
    const int n8W = (HID * HID) / 8;        // 524288
    const int n8X = in_sizes[0] / 8;        // 2097152
    const int grid = (8192 / BM) * (HID / BN);   // 512

    if (ws_size >= 56 * MB) {
        // disjoint: Xb [0,32M), Wb [32,40M), Wf [40,56M)
        u16*   Xb = (u16*)d_ws;
        u16*   Wb = (u16*)((char*)d_ws + 32 * MB);
        float* Wf = (float*)((char*)d_ws + 40 * MB);
        hipMemsetAsync(Wf, 0, (size_t)HID * HID * sizeof(float), stream);
        prep_kernel<<<2048, 256, 0, stream>>>(idx, vals, Wf, nnz, x, Xb, n8X);
        cvt_f32_bf16_kernel<<<2048, 256, 0, stream>>>(Wf, Wb, n8W);
        gemm3_kernel<<<grid, 512, 0, stream>>>(Xb, Wb, alpha, out);
    } else {
        // fallback overlapping layout (W consumed before Xb written)
        float* Wf = (float*)d_ws;
        u16*   Xb = (u16*)d_ws;
        u16*   Wb = (u16*)((char*)d_ws + 32 * MB);
        hipMemsetAsync(Wf, 0, (size_t)HID * HID * sizeof(float), stream);
        scatter_coo_kernel<<<(nnz + 255) / 256, 256, 0, stream>>>(idx, vals, Wf, nnz);
        cvt_f32_bf16_kernel<<<2048, 256, 0, stream>>>(Wf, Wb, n8W);
        cvt_f32_bf16_kernel<<<2048, 256, 0, stream>>>(x, Xb, n8X);
        gemm3_kernel<<<grid, 512, 0, stream>>>(Xb, Wb, alpha, out);
    }
}